// Round 3
// baseline (104.919 us; speedup 1.0000x reference)
//
#include <hip/hip_runtime.h>
#include <math.h>

#define BN 256      // batch
#define CN 2048     // channels
#define C4 512      // CN/4
#define EPSF 1e-12f
#define NBLK 512
#define MAGIC 0x5a17c0deu

// ---------------------------------------------------------------------------
// Fused kernel.
// Phase 1 (all 512 blocks): raw Gram tile D[i0:i0+4, j0:j0+32] = in @ in^T,
//   K=2048 fp32. Wave's k-slice of the 4 i-rows lives in 128 VGPRs; per j:
//   8 coalesced float4 loads of row j (L2-resident), 128 FMAs, butterfly.
//   Then: release-store flags[blockIdx] = MAGIC (agent scope -> L2 writeback,
//   required across non-coherent XCD L2s).
// Phase 2 (block 511 only): spin on all 512 flags with acquire loads (agent
//   scope -> cache invalidate), then compute the last-center loss from D:
//   s_i  = mean over center rows m of D[i,m];  cc = mean_m s_m = ||c||^2
//   nrm2 = D[i,i] - 2 s_i + cc;  angle[i,j] = (D[i,j]-s_i-s_j+cc)*inv_i*inv_j
//   pos/neg/exp/sum exactly as the reference (only the LAST center matters).
// Poison-safety: flags and D share d_ws, so they are re-poisoned together;
// stale-MAGIC (if ever) implies stale-but-identical D (deterministic), so the
// finisher result is correct either way.
// ---------------------------------------------------------------------------
__global__ __launch_bounds__(256) void fused_kernel(const float* __restrict__ in,
                                                    const int* __restrict__ targets,
                                                    float* __restrict__ D,
                                                    unsigned int* __restrict__ flags,
                                                    float* __restrict__ out) {
    const int b    = blockIdx.x;
    const int i0   = (b >> 3) * 4;
    const int j0   = (b & 7) * 32;
    const int tid  = threadIdx.x;
    const int lane = tid & 63;
    const int wave = tid >> 6;

    const float4* __restrict__ in4 = (const float4*)in;

    // ---------------- producer phase ----------------
    {
        float4 a[4][8];
#pragma unroll
        for (int r = 0; r < 4; ++r)
#pragma unroll
            for (int t = 0; t < 8; ++t)
                a[r][t] = in4[(i0 + r) * C4 + lane + 64 * t];

#pragma unroll 2
        for (int s = 0; s < 8; ++s) {
            const int j = j0 + wave + 4 * s;
            float4 bv[8];
#pragma unroll
            for (int t = 0; t < 8; ++t)
                bv[t] = in4[j * C4 + lane + 64 * t];

            float a0 = 0.f, a1 = 0.f, a2 = 0.f, a3 = 0.f;
#pragma unroll
            for (int t = 0; t < 8; ++t) {
                const float4 b4 = bv[t];
                a0 += a[0][t].x * b4.x + a[0][t].y * b4.y + a[0][t].z * b4.z + a[0][t].w * b4.w;
                a1 += a[1][t].x * b4.x + a[1][t].y * b4.y + a[1][t].z * b4.z + a[1][t].w * b4.w;
                a2 += a[2][t].x * b4.x + a[2][t].y * b4.y + a[2][t].z * b4.z + a[2][t].w * b4.w;
                a3 += a[3][t].x * b4.x + a[3][t].y * b4.y + a[3][t].z * b4.z + a[3][t].w * b4.w;
            }
#pragma unroll
            for (int off = 32; off >= 1; off >>= 1) {
                a0 += __shfl_xor(a0, off, 64);
                a1 += __shfl_xor(a1, off, 64);
                a2 += __shfl_xor(a2, off, 64);
                a3 += __shfl_xor(a3, off, 64);
            }
            if (lane < 4) {
                const float val = (lane == 0) ? a0 : (lane == 1) ? a1
                                : (lane == 2) ? a2 : a3;
                D[(i0 + lane) * BN + j] = val;
            }
        }
    }

    __syncthreads();               // drains vmcnt for all waves' D stores
    if (tid == 0) {
        __threadfence();           // device-scope: L2 writeback of D tile
        __hip_atomic_store(&flags[b], MAGIC, __ATOMIC_RELEASE, __HIP_MEMORY_SCOPE_AGENT);
    }
    if (b != NBLK - 1) return;

    // ---------------- finisher phase (block 511 only) ----------------
    while (__hip_atomic_load(&flags[tid], __ATOMIC_ACQUIRE, __HIP_MEMORY_SCOPE_AGENT) != MAGIC) {}
    while (__hip_atomic_load(&flags[tid + 256], __ATOMIC_ACQUIRE, __HIP_MEMORY_SCOPE_AGENT) != MAGIC) {}
    __syncthreads();               // all flags observed -> all D visible (acquire)

    __shared__ int   s_t[BN];
    __shared__ float s_s[BN];
    __shared__ float s_inv[BN];
    __shared__ int   s_idx[64];
    __shared__ int   s_cnt;
    __shared__ float s_cc;
    __shared__ float s_red[4];

    if (tid == 0) s_cnt = 0;
    s_t[tid] = targets[tid];
    __syncthreads();
    const int tc = s_t[BN - 4];                  // last center's target id
    if (s_t[tid] == tc) { int p = atomicAdd(&s_cnt, 1); s_idx[p] = tid; }
    __syncthreads();
    const int   cnt  = s_cnt;
    const float invc = 1.0f / (float)cnt;

    float si = 0.f;
    for (int m = 0; m < cnt; ++m) si += D[tid * BN + s_idx[m]];
    si *= invc;
    s_s[tid] = si;
    __syncthreads();
    if (tid == 0) {
        float cc = 0.f;
        for (int m = 0; m < cnt; ++m) cc += s_s[s_idx[m]];
        s_cc = cc * invc;
    }
    __syncthreads();
    const float cc   = s_cc;
    const float dii  = D[tid * BN + tid];
    const float nrm2 = fmaxf(dii - 2.f * si + cc, 0.f);
    const float inv  = 1.0f / fmaxf(sqrtf(nrm2), EPSF);
    s_inv[tid] = inv;
    __syncthreads();

    const int ti = s_t[tid];
    float pos = INFINITY;
    float neg = 0.f;
    const float4* __restrict__ D4 = (const float4*)D;
    for (int j4 = 0; j4 < BN / 4; ++j4) {
        const float4 d = D4[tid * (BN / 4) + j4];
        const int j = 4 * j4;
        const float g0 = (d.x - si - s_s[j + 0] + cc) * inv * s_inv[j + 0];
        const float g1 = (d.y - si - s_s[j + 1] + cc) * inv * s_inv[j + 1];
        const float g2 = (d.z - si - s_s[j + 2] + cc) * inv * s_inv[j + 2];
        const float g3 = (d.w - si - s_s[j + 3] + cc) * inv * s_inv[j + 3];
        if (s_t[j + 0] == ti) pos = fminf(pos, g0); else neg = fmaxf(neg, fmaxf(g0, 0.f));
        if (s_t[j + 1] == ti) pos = fminf(pos, g1); else neg = fmaxf(neg, fmaxf(g1, 0.f));
        if (s_t[j + 2] == ti) pos = fminf(pos, g2); else neg = fmaxf(neg, fmaxf(g2, 0.f));
        if (s_t[j + 3] == ti) pos = fminf(pos, g3); else neg = fmaxf(neg, fmaxf(g3, 0.f));
    }
    float val = expf(neg - pos);
#pragma unroll
    for (int off = 32; off >= 1; off >>= 1) val += __shfl_xor(val, off, 64);
    if ((tid & 63) == 0) s_red[tid >> 6] = val;
    __syncthreads();
    if (tid == 0)
        out[0] = (s_red[0] + s_red[1] + s_red[2] + s_red[3]) * (1.0f / 448.0f);
}

extern "C" void kernel_launch(void* const* d_in, const int* in_sizes, int n_in,
                              void* d_out, int out_size, void* d_ws, size_t ws_size,
                              hipStream_t stream) {
    const float* in      = (const float*)d_in[0];
    const int*   targets = (const int*)d_in[1];
    // d_in[2] (subs) is unused by the reference.

    float*        D     = (float*)d_ws;                 // 256*256 floats = 256 KB
    unsigned int* flags = (unsigned int*)(D + BN * BN); // 512 flags
    float*        out   = (float*)d_out;

    fused_kernel<<<NBLK, 256, 0, stream>>>(in, targets, D, flags, out);
}

// Round 4
// 92.158 us; speedup vs baseline: 1.1385x; 1.1385x over previous
//
#include <hip/hip_runtime.h>
#include <math.h>

#define BN 256      // batch
#define CN 2048     // channels
#define C4 512      // CN/4
#define EPSF 1e-12f

// ---------------------------------------------------------------------------
// Kernel A: raw Gram D = in @ in^T  (256x256, K=2048), fp32.
// 512 blocks: block = 4 i-rows x 32 j-cols. Wave's k-slice of the 4 i-rows
// lives in 128 VGPRs (wave-invariant across j). Per j: 8 coalesced float4
// global loads of row j (L2-resident), 128 FMAs, 64-lane butterfly, store.
// __launch_bounds__(256,1): explicitly allow the full VGPR budget — round 3
// showed that if the allocator demotes a[4][8] (VGPR 88, remat/spill), the
// kernel slows ~10x. Standalone compilation + (256,1) keeps it register-
// resident.
// ---------------------------------------------------------------------------
__global__ __launch_bounds__(256, 1) void gram_kernel(const float* __restrict__ in,
                                                      float* __restrict__ D) {
    const int b    = blockIdx.x;
    const int i0   = (b >> 3) * 4;
    const int j0   = (b & 7) * 32;
    const int tid  = threadIdx.x;
    const int lane = tid & 63;
    const int wave = tid >> 6;

    const float4* __restrict__ in4 = (const float4*)in;

    float4 a[4][8];
#pragma unroll
    for (int r = 0; r < 4; ++r)
#pragma unroll
        for (int t = 0; t < 8; ++t)
            a[r][t] = in4[(i0 + r) * C4 + lane + 64 * t];

#pragma unroll 2
    for (int s = 0; s < 8; ++s) {
        const int j = j0 + wave + 4 * s;
        float4 bv[8];
#pragma unroll
        for (int t = 0; t < 8; ++t)
            bv[t] = in4[j * C4 + lane + 64 * t];

        float a0 = 0.f, a1 = 0.f, a2 = 0.f, a3 = 0.f;
#pragma unroll
        for (int t = 0; t < 8; ++t) {
            const float4 b4 = bv[t];
            a0 += a[0][t].x * b4.x + a[0][t].y * b4.y + a[0][t].z * b4.z + a[0][t].w * b4.w;
            a1 += a[1][t].x * b4.x + a[1][t].y * b4.y + a[1][t].z * b4.z + a[1][t].w * b4.w;
            a2 += a[2][t].x * b4.x + a[2][t].y * b4.y + a[2][t].z * b4.z + a[2][t].w * b4.w;
            a3 += a[3][t].x * b4.x + a[3][t].y * b4.y + a[3][t].z * b4.z + a[3][t].w * b4.w;
        }
#pragma unroll
        for (int off = 32; off >= 1; off >>= 1) {
            a0 += __shfl_xor(a0, off, 64);
            a1 += __shfl_xor(a1, off, 64);
            a2 += __shfl_xor(a2, off, 64);
            a3 += __shfl_xor(a3, off, 64);
        }
        if (lane < 4) {
            const float val = (lane == 0) ? a0 : (lane == 1) ? a1
                            : (lane == 2) ? a2 : a3;
            D[(i0 + lane) * BN + j] = val;
        }
    }
}

// ---------------------------------------------------------------------------
// Kernel B: everything else from D. One block, thread i = row i.
//   s_i  = mean over center rows m of D[i,m]
//   cc   = mean over center rows m of s_m          (= ||c||^2)
//   nrm2 = D[i,i] - 2 s_i + cc                     (= ||in_i - c||^2)
//   angle[i,j] = (D[i,j] - s_i - s_j + cc) * inv_i * inv_j
//   pos/neg/exp/sum as in the reference (only the LAST center is returned).
// ---------------------------------------------------------------------------
__global__ __launch_bounds__(256) void finish_kernel(const float* __restrict__ D,
                                                     const int* __restrict__ targets,
                                                     float* __restrict__ out) {
    const int tid = threadIdx.x;
    __shared__ int   s_t[BN];
    __shared__ float s_s[BN];
    __shared__ float s_inv[BN];
    __shared__ int   s_idx[64];
    __shared__ int   s_cnt;
    __shared__ float s_cc;
    __shared__ float s_red[4];

    if (tid == 0) s_cnt = 0;
    s_t[tid] = targets[tid];
    __syncthreads();
    const int tc = s_t[BN - 4];                  // last center's target id
    if (s_t[tid] == tc) { int p = atomicAdd(&s_cnt, 1); s_idx[p] = tid; }
    __syncthreads();
    const int   cnt  = s_cnt;
    const float invc = 1.0f / (float)cnt;

    float si = 0.f;
    for (int m = 0; m < cnt; ++m) si += D[tid * BN + s_idx[m]];
    si *= invc;
    s_s[tid] = si;
    __syncthreads();
    if (tid == 0) {
        float cc = 0.f;
        for (int m = 0; m < cnt; ++m) cc += s_s[s_idx[m]];
        s_cc = cc * invc;
    }
    __syncthreads();
    const float cc   = s_cc;
    const float dii  = D[tid * BN + tid];
    const float nrm2 = fmaxf(dii - 2.f * si + cc, 0.f);
    const float inv  = 1.0f / fmaxf(sqrtf(nrm2), EPSF);
    s_inv[tid] = inv;
    __syncthreads();

    const int ti = s_t[tid];
    float pos = INFINITY;
    float neg = 0.f;
    const float4* __restrict__ D4 = (const float4*)D;
    for (int j4 = 0; j4 < BN / 4; ++j4) {
        const float4 d = D4[tid * (BN / 4) + j4];
        const int j = 4 * j4;
        const float g0 = (d.x - si - s_s[j + 0] + cc) * inv * s_inv[j + 0];
        const float g1 = (d.y - si - s_s[j + 1] + cc) * inv * s_inv[j + 1];
        const float g2 = (d.z - si - s_s[j + 2] + cc) * inv * s_inv[j + 2];
        const float g3 = (d.w - si - s_s[j + 3] + cc) * inv * s_inv[j + 3];
        if (s_t[j + 0] == ti) pos = fminf(pos, g0); else neg = fmaxf(neg, fmaxf(g0, 0.f));
        if (s_t[j + 1] == ti) pos = fminf(pos, g1); else neg = fmaxf(neg, fmaxf(g1, 0.f));
        if (s_t[j + 2] == ti) pos = fminf(pos, g2); else neg = fmaxf(neg, fmaxf(g2, 0.f));
        if (s_t[j + 3] == ti) pos = fminf(pos, g3); else neg = fmaxf(neg, fmaxf(g3, 0.f));
    }
    float val = expf(neg - pos);
#pragma unroll
    for (int off = 32; off >= 1; off >>= 1) val += __shfl_xor(val, off, 64);
    if ((tid & 63) == 0) s_red[tid >> 6] = val;
    __syncthreads();
    if (tid == 0)
        out[0] = (s_red[0] + s_red[1] + s_red[2] + s_red[3]) * (1.0f / 448.0f);
}

extern "C" void kernel_launch(void* const* d_in, const int* in_sizes, int n_in,
                              void* d_out, int out_size, void* d_ws, size_t ws_size,
                              hipStream_t stream) {
    const float* in      = (const float*)d_in[0];
    const int*   targets = (const int*)d_in[1];
    // d_in[2] (subs) is unused by the reference.

    float* D   = (float*)d_ws;               // 256*256 floats = 256 KB
    float* out = (float*)d_out;

    gram_kernel  <<<512, 256, 0, stream>>>(in, D);
    finish_kernel<<<1,   256, 0, stream>>>(D, targets, out);
}

// Round 5
// 90.127 us; speedup vs baseline: 1.1641x; 1.0225x over previous
//
#include <hip/hip_runtime.h>
#include <math.h>

#define BN 256      // batch
#define CN 2048     // channels
#define C4 512      // CN/4
#define EPSF 1e-12f

// ---------------------------------------------------------------------------
// Kernel A: raw Gram D = in @ in^T  (256x256, K=2048), fp32.
// 512 blocks: block = 4 i-rows x 32 j-cols. Wave's k-slice of the 4 i-rows
// lives in 128 VGPRs (wave-invariant across j). Per j: 8 coalesced float4
// global loads of row j (L2-resident), 128 FMAs, merge-tree reduction, store.
//
// Reduction: merge-tree, 7 shuffles per s-step (was 24 with 4 independent
// butterflies). xor-1 and xor-2 levels swap-select so two accumulators merge
// per shuffle; after them lane l holds the partial of acc (l&3); xor-4..32
// butterfly finishes. Lane r in {0..3} ends with the full sum of acc r.
// DS-pipe ops/CU: 1536 -> 448 (~-2.5us of serialized LDS-pipe time).
//
// __launch_bounds__(256,1): round 3 showed demoting a[4][8] (VGPR 88) costs
// ~10x; keep the full VGPR budget available.
// ---------------------------------------------------------------------------
__global__ __launch_bounds__(256, 1) void gram_kernel(const float* __restrict__ in,
                                                      float* __restrict__ D) {
    const int b    = blockIdx.x;
    const int i0   = (b >> 3) * 4;
    const int j0   = (b & 7) * 32;
    const int tid  = threadIdx.x;
    const int lane = tid & 63;
    const int wave = tid >> 6;

    const bool odd1 = (lane & 1);
    const bool odd2 = (lane & 2);

    const float4* __restrict__ in4 = (const float4*)in;

    float4 a[4][8];
#pragma unroll
    for (int r = 0; r < 4; ++r)
#pragma unroll
        for (int t = 0; t < 8; ++t)
            a[r][t] = in4[(i0 + r) * C4 + lane + 64 * t];

#pragma unroll 2
    for (int s = 0; s < 8; ++s) {
        const int j = j0 + wave + 4 * s;
        float4 bv[8];
#pragma unroll
        for (int t = 0; t < 8; ++t)
            bv[t] = in4[j * C4 + lane + 64 * t];

        float a0 = 0.f, a1 = 0.f, a2 = 0.f, a3 = 0.f;
#pragma unroll
        for (int t = 0; t < 8; ++t) {
            const float4 b4 = bv[t];
            a0 += a[0][t].x * b4.x + a[0][t].y * b4.y + a[0][t].z * b4.z + a[0][t].w * b4.w;
            a1 += a[1][t].x * b4.x + a[1][t].y * b4.y + a[1][t].z * b4.z + a[1][t].w * b4.w;
            a2 += a[2][t].x * b4.x + a[2][t].y * b4.y + a[2][t].z * b4.z + a[2][t].w * b4.w;
            a3 += a[3][t].x * b4.x + a[3][t].y * b4.y + a[3][t].z * b4.z + a[3][t].w * b4.w;
        }

        // merge level 1 (xor 1): c01 holds acc (lane&1), c23 holds acc 2+(lane&1)
        const float c01 = (odd1 ? a1 : a0) + __shfl_xor(odd1 ? a0 : a1, 1, 64);
        const float c23 = (odd1 ? a3 : a2) + __shfl_xor(odd1 ? a2 : a3, 1, 64);
        // merge level 2 (xor 2): c holds acc (lane&3), partial over 4-lane group
        float c = (odd2 ? c23 : c01) + __shfl_xor(odd2 ? c01 : c23, 2, 64);
        // butterfly the remaining 16 groups
        c += __shfl_xor(c, 4, 64);
        c += __shfl_xor(c, 8, 64);
        c += __shfl_xor(c, 16, 64);
        c += __shfl_xor(c, 32, 64);

        if (lane < 4)
            D[(i0 + lane) * BN + j] = c;   // lane r carries acc r
    }
}

// ---------------------------------------------------------------------------
// Kernel B: everything else from D. One block, thread i = row i.
//   s_i  = mean over center rows m of D[m,i]   (row read: coalesced; D symm.)
//   cc   = mean over center rows m of s_m          (= ||c||^2)
//   nrm2 = D[i,i] - 2 s_i + cc                     (= ||in_i - c||^2)
//   angle[i,j] = (D[i,j] - s_i - s_j + cc) * inv_i * inv_j
//   pos/neg/exp/sum as in the reference (only the LAST center is returned).
// ---------------------------------------------------------------------------
__global__ __launch_bounds__(256) void finish_kernel(const float* __restrict__ D,
                                                     const int* __restrict__ targets,
                                                     float* __restrict__ out) {
    const int tid = threadIdx.x;
    __shared__ int   s_t[BN];
    __shared__ float s_s[BN];
    __shared__ float s_inv[BN];
    __shared__ int   s_idx[64];
    __shared__ int   s_cnt;
    __shared__ float s_cc;
    __shared__ float s_red[4];

    if (tid == 0) s_cnt = 0;
    s_t[tid] = targets[tid];
    __syncthreads();
    const int tc = s_t[BN - 4];                  // last center's target id
    if (s_t[tid] == tc) { int p = atomicAdd(&s_cnt, 1); s_idx[p] = tid; }
    __syncthreads();
    const int   cnt  = s_cnt;
    const float invc = 1.0f / (float)cnt;

    float si = 0.f;
    for (int m = 0; m < cnt; ++m) si += D[s_idx[m] * BN + tid];   // coalesced
    si *= invc;
    s_s[tid] = si;
    __syncthreads();
    if (tid == 0) {
        float cc = 0.f;
        for (int m = 0; m < cnt; ++m) cc += s_s[s_idx[m]];
        s_cc = cc * invc;
    }
    __syncthreads();
    const float cc   = s_cc;
    const float dii  = D[tid * BN + tid];
    const float nrm2 = fmaxf(dii - 2.f * si + cc, 0.f);
    const float inv  = 1.0f / fmaxf(sqrtf(nrm2), EPSF);
    s_inv[tid] = inv;
    __syncthreads();

    const int ti = s_t[tid];
    float pos = INFINITY;
    float neg = 0.f;
    const float4* __restrict__ D4 = (const float4*)D;
    for (int j4 = 0; j4 < BN / 4; ++j4) {
        const float4 d = D4[tid * (BN / 4) + j4];
        const int j = 4 * j4;
        const float g0 = (d.x - si - s_s[j + 0] + cc) * inv * s_inv[j + 0];
        const float g1 = (d.y - si - s_s[j + 1] + cc) * inv * s_inv[j + 1];
        const float g2 = (d.z - si - s_s[j + 2] + cc) * inv * s_inv[j + 2];
        const float g3 = (d.w - si - s_s[j + 3] + cc) * inv * s_inv[j + 3];
        if (s_t[j + 0] == ti) pos = fminf(pos, g0); else neg = fmaxf(neg, fmaxf(g0, 0.f));
        if (s_t[j + 1] == ti) pos = fminf(pos, g1); else neg = fmaxf(neg, fmaxf(g1, 0.f));
        if (s_t[j + 2] == ti) pos = fminf(pos, g2); else neg = fmaxf(neg, fmaxf(g2, 0.f));
        if (s_t[j + 3] == ti) pos = fminf(pos, g3); else neg = fmaxf(neg, fmaxf(g3, 0.f));
    }
    float val = expf(neg - pos);
#pragma unroll
    for (int off = 32; off >= 1; off >>= 1) val += __shfl_xor(val, off, 64);
    if ((tid & 63) == 0) s_red[tid >> 6] = val;
    __syncthreads();
    if (tid == 0)
        out[0] = (s_red[0] + s_red[1] + s_red[2] + s_red[3]) * (1.0f / 448.0f);
}

extern "C" void kernel_launch(void* const* d_in, const int* in_sizes, int n_in,
                              void* d_out, int out_size, void* d_ws, size_t ws_size,
                              hipStream_t stream) {
    const float* in      = (const float*)d_in[0];
    const int*   targets = (const int*)d_in[1];
    // d_in[2] (subs) is unused by the reference.

    float* D   = (float*)d_ws;               // 256*256 floats = 256 KB
    float* out = (float*)d_out;

    gram_kernel  <<<512, 256, 0, stream>>>(in, D);
    finish_kernel<<<1,   256, 0, stream>>>(D, targets, out);
}

// Round 6
// 85.663 us; speedup vs baseline: 1.2248x; 1.0521x over previous
//
#include <hip/hip_runtime.h>
#include <math.h>

#define BN 256      // batch
#define CN 2048     // channels
#define C4 512      // CN/4
#define EPSF 1e-12f

// ---------------------------------------------------------------------------
// Kernel A: raw Gram D = in @ in^T (256x256, K=2048), fp32, SYMMETRIC.
// Grid 512 (tile ib=b>>3 of 4 i-rows, jb=b&7 of 32 j-cols); tiles entirely in
// the strict lower triangle (32*jb+31 < 4*ib) exit early — their region is
// covered by the mirror store of the transposed tile. D[i,j] and D[j,i] are
// bitwise identical (commutative products, same summation order), so double
// writes on straddling tiles are benign. Block 64 (always an exit block)
// zeroes out[0] for finish's atomicAdd; kernel boundary orders it.
// Per kept tile: 4 i-rows in 128 VGPRs (wave-invariant), per j 8 coalesced
// float4 loads + 128 FMAs + 7-shuffle merge-tree; lanes 0-3 store c and its
// mirror. L2 traffic 147 MB -> ~83 MB, FMAs x0.56.
// __launch_bounds__(256,1): round 3 showed demoting a[4][8] costs ~10x.
// ---------------------------------------------------------------------------
__global__ __launch_bounds__(256, 1) void gram_kernel(const float* __restrict__ in,
                                                      float* __restrict__ D,
                                                      float* __restrict__ out) {
    const int b   = blockIdx.x;
    const int ib  = b >> 3;
    const int jb  = b & 7;
    const int tid = threadIdx.x;

    if (32 * jb + 31 < 4 * ib) {           // strictly-lower tile: mirror-covered
        if (b == 64 && tid == 0) out[0] = 0.f;
        return;
    }

    const int i0   = ib * 4;
    const int j0   = jb * 32;
    const int lane = tid & 63;
    const int wave = tid >> 6;
    const bool odd1 = (lane & 1);
    const bool odd2 = (lane & 2);

    const float4* __restrict__ in4 = (const float4*)in;

    float4 a[4][8];
#pragma unroll
    for (int r = 0; r < 4; ++r)
#pragma unroll
        for (int t = 0; t < 8; ++t)
            a[r][t] = in4[(i0 + r) * C4 + lane + 64 * t];

#pragma unroll 2
    for (int s = 0; s < 8; ++s) {
        const int j = j0 + wave + 4 * s;
        float4 bv[8];
#pragma unroll
        for (int t = 0; t < 8; ++t)
            bv[t] = in4[j * C4 + lane + 64 * t];

        float a0 = 0.f, a1 = 0.f, a2 = 0.f, a3 = 0.f;
#pragma unroll
        for (int t = 0; t < 8; ++t) {
            const float4 b4 = bv[t];
            a0 += a[0][t].x * b4.x + a[0][t].y * b4.y + a[0][t].z * b4.z + a[0][t].w * b4.w;
            a1 += a[1][t].x * b4.x + a[1][t].y * b4.y + a[1][t].z * b4.z + a[1][t].w * b4.w;
            a2 += a[2][t].x * b4.x + a[2][t].y * b4.y + a[2][t].z * b4.z + a[2][t].w * b4.w;
            a3 += a[3][t].x * b4.x + a[3][t].y * b4.y + a[3][t].z * b4.z + a[3][t].w * b4.w;
        }

        // merge-tree reduction: 7 shuffles, lane r in {0..3} ends with acc r
        const float c01 = (odd1 ? a1 : a0) + __shfl_xor(odd1 ? a0 : a1, 1, 64);
        const float c23 = (odd1 ? a3 : a2) + __shfl_xor(odd1 ? a2 : a3, 1, 64);
        float c = (odd2 ? c23 : c01) + __shfl_xor(odd2 ? c01 : c23, 2, 64);
        c += __shfl_xor(c, 4, 64);
        c += __shfl_xor(c, 8, 64);
        c += __shfl_xor(c, 16, 64);
        c += __shfl_xor(c, 32, 64);

        if (lane < 4) {
            const int i = i0 + lane;
            D[i * BN + j] = c;
            D[j * BN + i] = c;             // mirror (bitwise-identical value)
        }
    }
}

// ---------------------------------------------------------------------------
// Kernel B: loss from D. Grid 8 x 256; block handles 32 rows. Every block
// recomputes s_s/s_inv (cheap, deterministic: thread-0 sequential center-row
// scan -> bitwise-identical across blocks).
//   s_i  = mean over center rows m of D[m,i]   (coalesced; D symmetric)
//   cc   = mean_m s_m = ||c||^2;  nrm2 = D[i,i] - 2 s_i + cc
//   angle[i,j] = (D[i,j]-s_i-s_j+cc)*inv_i*inv_j; pos/neg/exp as reference.
// Row layout: 8 threads per row (sub = tid&7 covers 32 j's); pos/neg reduced
// via shfl_xor 1/2/4 (sub-group is contiguous lanes); block sum -> one
// atomicAdd into out[0] (zeroed by gram's block 64).
// ---------------------------------------------------------------------------
__global__ __launch_bounds__(256) void finish_kernel(const float* __restrict__ D,
                                                     const int* __restrict__ targets,
                                                     float* __restrict__ out) {
    const int tid = threadIdx.x;
    const int blk = blockIdx.x;

    __shared__ int   s_t[BN];
    __shared__ float s_s[BN];
    __shared__ float s_inv[BN];
    __shared__ int   s_idx[64];
    __shared__ int   s_cnt;
    __shared__ float s_cc;
    __shared__ float s_red[4];

    s_t[tid] = targets[tid];
    __syncthreads();
    const int tc = s_t[BN - 4];                  // last center's target id
    if (tid == 0) {                              // deterministic index order
        int c = 0;
        for (int m = 0; m < BN; ++m)
            if (s_t[m] == tc) s_idx[c++] = m;
        s_cnt = c;
    }
    __syncthreads();
    const int   cnt  = s_cnt;
    const float invc = 1.0f / (float)cnt;

    float si = 0.f;
    for (int m = 0; m < cnt; ++m) si += D[s_idx[m] * BN + tid];   // coalesced
    si *= invc;
    s_s[tid] = si;
    __syncthreads();
    if (tid == 0) {
        float cc = 0.f;
        for (int m = 0; m < cnt; ++m) cc += s_s[s_idx[m]];
        s_cc = cc * invc;
    }
    __syncthreads();
    const float cc   = s_cc;
    const float dii  = D[tid * BN + tid];
    const float nrm2 = fmaxf(dii - 2.f * si + cc, 0.f);
    const float inv  = 1.0f / fmaxf(sqrtf(nrm2), EPSF);
    s_inv[tid] = inv;
    __syncthreads();

    const int   row  = blk * 32 + (tid >> 3);
    const int   sub  = tid & 7;
    const int   ti   = s_t[row];
    const float siR  = s_s[row];
    const float invR = s_inv[row];

    float pos = INFINITY;
    float neg = 0.f;
    const float4* __restrict__ D4 = (const float4*)D;
#pragma unroll
    for (int q = 0; q < 8; ++q) {
        const int j4 = sub * 8 + q;
        const float4 d = D4[row * (BN / 4) + j4];
        const int j = 4 * j4;
        const float g0 = (d.x - siR - s_s[j + 0] + cc) * invR * s_inv[j + 0];
        const float g1 = (d.y - siR - s_s[j + 1] + cc) * invR * s_inv[j + 1];
        const float g2 = (d.z - siR - s_s[j + 2] + cc) * invR * s_inv[j + 2];
        const float g3 = (d.w - siR - s_s[j + 3] + cc) * invR * s_inv[j + 3];
        if (s_t[j + 0] == ti) pos = fminf(pos, g0); else neg = fmaxf(neg, fmaxf(g0, 0.f));
        if (s_t[j + 1] == ti) pos = fminf(pos, g1); else neg = fmaxf(neg, fmaxf(g1, 0.f));
        if (s_t[j + 2] == ti) pos = fminf(pos, g2); else neg = fmaxf(neg, fmaxf(g2, 0.f));
        if (s_t[j + 3] == ti) pos = fminf(pos, g3); else neg = fmaxf(neg, fmaxf(g3, 0.f));
    }
    // reduce pos/neg across the 8 sub-threads of this row (contiguous lanes)
#pragma unroll
    for (int off = 1; off <= 4; off <<= 1) {
        pos = fminf(pos, __shfl_xor(pos, off, 64));
        neg = fmaxf(neg, __shfl_xor(neg, off, 64));
    }
    float val = (sub == 0) ? expf(neg - pos) : 0.f;
#pragma unroll
    for (int off = 1; off <= 32; off <<= 1) val += __shfl_xor(val, off, 64);
    if ((tid & 63) == 0) s_red[tid >> 6] = val;
    __syncthreads();
    if (tid == 0)
        atomicAdd(out, (s_red[0] + s_red[1] + s_red[2] + s_red[3]) * (1.0f / 448.0f));
}

extern "C" void kernel_launch(void* const* d_in, const int* in_sizes, int n_in,
                              void* d_out, int out_size, void* d_ws, size_t ws_size,
                              hipStream_t stream) {
    const float* in      = (const float*)d_in[0];
    const int*   targets = (const int*)d_in[1];
    // d_in[2] (subs) is unused by the reference.

    float* D   = (float*)d_ws;               // 256*256 floats = 256 KB
    float* out = (float*)d_out;

    gram_kernel  <<<512, 256, 0, stream>>>(in, D, out);
    finish_kernel<<<8,   256, 0, stream>>>(D, targets, out);
}